// Round 1
// baseline (545.342 us; speedup 1.0000x reference)
//
#include <hip/hip_runtime.h>
#include <hip/hip_fp16.h>

// Fused neural-CA step on MI355X (gfx950).
//   z  = leaky(depthwise_conv5x5_D4sym(psi) + b1)
//   h  = leaky(w2 z + b2);  out = tanh(psi + w3 h + b3)
//
// Design (round 1):
//  - 1 block = 1 (image, 16-row slab); grid 2048*4, block 256 (4 waves).
//  - psi slab staged in LDS as fp16 pairs (__half2), stride 35 pairs/row
//    (70 halves) -> all phase-1 read patterns are exactly 2-way bank
//    aliased (free on CDNA4, m136).
//  - D4 symmetry: kernel has 6 unique weights (A..F). Vertical pair sums
//    r0/r1/r2 + horizontal symmetric taps -> 6 FMA + ~9 add per output,
//    50 ds_read_b32 per 16-output segment (vs 200 naive scalar).
//  - z kept in LDS as fp16 pairs (stride 33 pairs) -> 39.5 KB LDS total,
//    4 blocks/CU, 16 waves/CU.
//  - mix phase: thread owns 2 adjacent pixels (x even) -> half2 z/psi
//    reads, float2 coalesced out stores. w2/b2/w3/b3 read with uniform
//    indices from global -> s_load (SMEM pipe), no LDS traffic.
//  - tanh(x) = 1 - 2*rcp(exp(2x)+1) via v_exp + v_rcp.

#define HIDDEN 8
#define RES    64
#define SLAB   16
#define SROWS  20   // SLAB + 4 halo rows
#define SSTR2  35   // psi tile row stride in __half2 units (70 halves)
#define ZSTR2  33   // z tile row stride in __half2 units (66 halves)

__global__ __launch_bounds__(256, 4)
void ca_fused(const float* __restrict__ psi,
              const float* __restrict__ filter1,
              const float* __restrict__ bias1,
              const float* __restrict__ w2,
              const float* __restrict__ b2,
              const float* __restrict__ w3,
              const float* __restrict__ b3,
              float* __restrict__ out)
{
    __shared__ __half2 s_in[HIDDEN * SROWS * SSTR2];  // 5600 pairs = 22400 B
    __shared__ __half2 s_z [HIDDEN * SLAB  * ZSTR2];  // 4224 pairs = 16896 B
    __shared__ float   s_coef[HIDDEN * 8];            // A,B,C,D,E,F,bias1,pad

    const int tid  = threadIdx.x;
    const int b    = blockIdx.x >> 2;
    const int slab = blockIdx.x & 3;
    const int y0   = slab * SLAB;

    const float* psib = psi + (size_t)b * (HIDDEN * RES * RES);

    // ---- totalistic coefficients, one thread per channel ----
    if (tid < HIDDEN) {
        const float* f = filter1 + tid * 25;
        float x[25];
        float m = 0.f;
        #pragma unroll
        for (int i = 0; i < 25; ++i) { x[i] = f[i]; m += x[i]; }
        m *= 0.04f;  // /25
        // orbits of D4 on the 5x5 grid (flat index i*5+j)
        float A = x[12] - m;                                          // center
        float B = 0.25f  * (x[7]+x[17]+x[11]+x[13]) - m;              // edge-1
        float C = 0.25f  * (x[6]+x[8]+x[16]+x[18]) - m;               // diag-1
        float D = 0.25f  * (x[2]+x[22]+x[10]+x[14]) - m;              // edge-2
        float E = 0.125f * (x[1]+x[3]+x[21]+x[23]+x[5]+x[15]+x[9]+x[19]) - m; // knight
        float F = 0.25f  * (x[0]+x[4]+x[20]+x[24]) - m;               // corner
        s_coef[tid*8+0] = A; s_coef[tid*8+1] = B; s_coef[tid*8+2] = C;
        s_coef[tid*8+3] = D; s_coef[tid*8+4] = E; s_coef[tid*8+5] = F;
        s_coef[tid*8+6] = bias1[tid];
    }

    // ---- stage psi slab into LDS as fp16 pairs (zero halo) ----
    // pairs px in [0,34): px 0 and 33 are the zero pad, 1..32 map to gx 0..63
    for (int p = tid; p < HIDDEN * SROWS * 34; p += 256) {
        int c   = p / (SROWS * 34);
        int rem = p - c * (SROWS * 34);
        int r   = rem / 34;
        int px  = rem - r * 34;
        int gy  = y0 - 2 + r;
        float2 v = make_float2(0.f, 0.f);
        if ((unsigned)gy < RES && px >= 1 && px <= 32)
            v = *(const float2*)(psib + ((c << 12) | (gy << 6)) + (2*px - 2));
        s_in[(c * SROWS + r) * SSTR2 + px] = __floats2half2_rn(v.x, v.y);
    }
    __syncthreads();

    // ---- phase 1: depthwise conv + bias + leaky -> s_z ----
    // job = (c, y, seg): 16 output cols starting at 16*seg of row y, chan c
    #pragma unroll
    for (int jj = 0; jj < 2; ++jj) {
        int job = tid + (jj << 8);
        int c   = job >> 6;            // wave-uniform
        int y   = (job >> 2) & 15;
        int seg = job & 3;
        int base = (c * SROWS + y) * SSTR2 + (seg << 3);

        float r0[20], r1[20], r2[20];  // vertical sums over 20 halo cols
        #pragma unroll
        for (int k = 0; k < 10; ++k) {
            __half2 p0 = s_in[base              + k];
            __half2 p1 = s_in[base +   SSTR2    + k];
            __half2 p2 = s_in[base + 2*SSTR2    + k];
            __half2 p3 = s_in[base + 3*SSTR2    + k];
            __half2 p4 = s_in[base + 4*SSTR2    + k];
            __half2 v1 = __hadd2(p1, p3);
            __half2 v2 = __hadd2(p0, p4);
            float2 f0 = __half22float2(p2);
            float2 f1 = __half22float2(v1);
            float2 f2 = __half22float2(v2);
            r0[2*k] = f0.x; r0[2*k+1] = f0.y;
            r1[2*k] = f1.x; r1[2*k+1] = f1.y;
            r2[2*k] = f2.x; r2[2*k+1] = f2.y;
        }
        float A  = s_coef[c*8+0], Bc = s_coef[c*8+1], Cc = s_coef[c*8+2];
        float Dc = s_coef[c*8+3], Ec = s_coef[c*8+4], Fc = s_coef[c*8+5];
        float bias = s_coef[c*8+6];

        int zbase = (c * SLAB + y) * ZSTR2 + (seg << 3);
        #pragma unroll
        for (int j2 = 0; j2 < 8; ++j2) {
            float vv[2];
            #pragma unroll
            for (int t = 0; t < 2; ++t) {
                int j = 2*j2 + t;
                float v = A  *  r0[j+2]
                        + Bc * (r0[j+1] + r0[j+3] + r1[j+2])
                        + Cc * (r1[j+1] + r1[j+3])
                        + Dc * (r0[j]   + r0[j+4] + r2[j+2])
                        + Ec * (r1[j]   + r1[j+4] + r2[j+1] + r2[j+3])
                        + Fc * (r2[j]   + r2[j+4])
                        + bias;
                vv[t] = fmaxf(v, 0.01f * v);   // leaky relu
            }
            s_z[zbase + j2] = __floats2half2_rn(vv[0], vv[1]);
        }
    }
    __syncthreads();

    // ---- phase 2: per-pixel 8x8 GEMMs + residual + tanh ----
    float* outb = out + (size_t)b * (HIDDEN * RES * RES);
    #pragma unroll
    for (int gg = 0; gg < 2; ++gg) {
        int q  = tid + (gg << 8);   // pixel-pair index, pixels (2q, 2q+1)
        int y  = q >> 5;
        int xh = q & 31;            // x0 = 2*xh

        float za[8], zb_[8];
        #pragma unroll
        for (int c = 0; c < 8; ++c) {
            float2 f = __half22float2(s_z[(c * SLAB + y) * ZSTR2 + xh]);
            za[c] = f.x; zb_[c] = f.y;
        }
        float ha[8], hb[8];
        #pragma unroll
        for (int o = 0; o < 8; ++o) {
            float a0 = b2[o], a1 = a0;          // uniform -> s_load
            #pragma unroll
            for (int i = 0; i < 8; ++i) {
                float w = w2[o*8+i];            // uniform -> s_load
                a0 = fmaf(w, za[i],  a0);
                a1 = fmaf(w, zb_[i], a1);
            }
            ha[o] = fmaxf(a0, 0.01f * a0);
            hb[o] = fmaxf(a1, 0.01f * a1);
        }
        #pragma unroll
        for (int o = 0; o < 8; ++o) {
            float g0 = b3[o], g1 = g0;
            #pragma unroll
            for (int i = 0; i < 8; ++i) {
                float w = w3[o*8+i];
                g0 = fmaf(w, ha[i], g0);
                g1 = fmaf(w, hb[i], g1);
            }
            float2 ps = __half22float2(s_in[(o * SROWS + y + 2) * SSTR2 + xh + 1]);
            float t0 = ps.x + g0;
            float t1 = ps.y + g1;
            // tanh(x) = 1 - 2/(exp(2x)+1); exp->inf / ->0 saturate correctly
            float e0 = __expf(2.f * t0);
            float e1 = __expf(2.f * t1);
            float o0 = 1.f - 2.f * __builtin_amdgcn_rcpf(e0 + 1.f);
            float o1 = 1.f - 2.f * __builtin_amdgcn_rcpf(e1 + 1.f);
            *(float2*)(outb + (o << 12) + ((y0 + y) << 6) + 2*xh) = make_float2(o0, o1);
        }
    }
}

extern "C" void kernel_launch(void* const* d_in, const int* in_sizes, int n_in,
                              void* d_out, int out_size, void* d_ws, size_t ws_size,
                              hipStream_t stream) {
    const float* psi     = (const float*)d_in[0];
    const float* filter1 = (const float*)d_in[1];
    const float* bias1   = (const float*)d_in[2];
    const float* w2      = (const float*)d_in[3];
    const float* b2      = (const float*)d_in[4];
    const float* w3      = (const float*)d_in[5];
    const float* b3      = (const float*)d_in[6];
    float* out = (float*)d_out;

    dim3 grid(2048 * 4);
    dim3 block(256);
    hipLaunchKernelGGL(ca_fused, grid, block, 0, stream,
                       psi, filter1, bias1, w2, b2, w3, b3, out);
}